// Round 6
// baseline (2551.035 us; speedup 1.0000x reference)
//
#include <hip/hip_runtime.h>
#include <hip/hip_fp16.h>
#include <cstdint>

typedef _Float16 f16;
typedef _Float16 f16x2 __attribute__((ext_vector_type(2)));
typedef _Float16 f16x4 __attribute__((ext_vector_type(4)));
typedef _Float16 f16x8 __attribute__((ext_vector_type(8)));
typedef float f32x4 __attribute__((ext_vector_type(4)));

#define kH 200
#define kG 800
#define kS 255
#define kW 512
#define kMid 127

// ---- ws layout (byte offsets), total ~213 MB ----
#define OFF_WF   209715200ULL   // 8 x [800x200] f16 weight matrices (rows permuted n'=4u+g)
#define OFF_BS   212275200ULL   // 4 x [800] f32 combined biases (permuted)
#define OFF_SENT 212288000ULL   // [255x200] f32 sentence embeddings
#define OFF_XPP  212492032ULL   // 2 x [128x800] f16 prev/post preactivations
#define OFF_OUTS 212901632ULL   // [400] f32 prev_out|post_out

__device__ __forceinline__ float sigf(float x) { return 1.0f / (1.0f + __expf(-x)); }
__device__ __forceinline__ float tanhf_(float x) { return 1.0f - 2.0f / (__expf(2.0f * x) + 1.0f); }

__device__ __forceinline__ const f16* sel4h(int s, const f16* a, const f16* b,
                                            const f16* c, const f16* d) {
  return s == 0 ? a : s == 1 ? b : s == 2 ? c : d;
}
__device__ __forceinline__ const float* sel4f(int s, const float* a, const float* b,
                                              const float* c, const float* d) {
  return s == 0 ? a : s == 1 ? b : s == 2 ? c : d;
}
__device__ __forceinline__ float* sel4o(int s, float* a, float* b, float* c, float* d) {
  return s == 0 ? a : s == 1 ? b : s == 2 ? c : d;
}

// ---------------- prep: f32->f16 weights (gate-unit interleaved rows), biases ----------------
// dst row n' = 4u+g  <->  src row n = g*200+u  (applied to all Wih/Whh and biases).
__global__ __launch_bounds__(256) void ABHUE_prep(
    const float* W0, const float* W1, const float* W2, const float* W3,
    const float* W4, const float* W5, const float* W6, const float* W7,
    const float* B0i, const float* B0h, const float* B1i, const float* B1h,
    const float* B2i, const float* B2h, const float* B3i, const float* B3h,
    f16* wdst, float* bdst)
{
  int idx = blockIdx.x * 256 + threadIdx.x;
  const int WN = kG * kH;  // 160000
  if (idx < 8 * WN) {
    int m = idx / WN, off = idx % WN;
    const float* src = m == 0 ? W0 : m == 1 ? W1 : m == 2 ? W2 : m == 3 ? W3
                     : m == 4 ? W4 : m == 5 ? W5 : m == 6 ? W6 : W7;
    int np = off / kH, k = off - np * kH;
    int u = np >> 2, g = np & 3;
    wdst[idx] = (f16)src[(size_t)(g * kH + u) * kH + k];
  } else {
    int j = idx - 8 * WN;
    if (j < 4 * kG) {
      int st = j / kG, np = j - st * kG;
      int u = np >> 2, g = np & 3;
      int n = g * kH + u;
      const float* bi = st == 0 ? B0i : st == 1 ? B1i : st == 2 ? B2i : B3i;
      const float* bh = st == 0 ? B0h : st == 1 ? B1h : st == 2 ? B2h : B3h;
      bdst[j] = bi[n] + bh[n];
    }
  }
}

// ---------------- GEMM: X[m, 0..799] = A[m,:200] @ W[800,200]^T + bias ----------------
#define BM 64
#define BKP 232
__global__ __launch_bounds__(256) void ABHUE_gemm_x(
    const float* __restrict__ A, const f16* __restrict__ Wf,
    const float* __restrict__ bias, f16* __restrict__ X, int rev)
{
  __shared__ __align__(16) f16 Al[BM * BKP];
  __shared__ __align__(16) f16 Bl[BM * BKP];
  int tid = threadIdx.x;
  int m0 = blockIdx.x * BM;

  #pragma unroll
  for (int it = 0; it < 4; ++it) {
    int idx = tid + 256 * it;
    int row = idx >> 4, dw = idx & 15;
    *(uint32_t*)(&Al[row * BKP + 200 + dw * 2]) = 0u;
    *(uint32_t*)(&Bl[row * BKP + 200 + dw * 2]) = 0u;
  }
  for (int it = 0; it < 13; ++it) {
    int q = tid + 256 * it;
    if (q < 3200) {
      int row = q / 50, c = q % 50;
      int rg = m0 + row; if (rev >= 0) rg = rev - rg;
      const float4 v = *(const float4*)(A + (size_t)rg * kH + c * 4);
      f16x2 p0; p0[0] = (f16)v.x; p0[1] = (f16)v.y;
      f16x2 p1; p1[0] = (f16)v.z; p1[1] = (f16)v.w;
      uint2 pk; pk.x = __builtin_bit_cast(uint32_t, p0); pk.y = __builtin_bit_cast(uint32_t, p1);
      *(uint2*)(&Al[row * BKP + c * 4]) = pk;
    }
  }
  int wv = tid >> 6, lane = tid & 63;
  int lr = lane & 15, lq = lane >> 4;

  for (int nt = 0; nt < 13; ++nt) {
    int n0 = nt * 64;
    __syncthreads();
    for (int it = 0; it < 7; ++it) {
      int q = tid + 256 * it;
      if (q < 1600) {
        int row = q / 25, c = q % 25;
        int ng = n0 + row;
        uint4 v = (ng < kG) ? *(const uint4*)(Wf + (size_t)ng * kH + c * 8)
                            : make_uint4(0, 0, 0, 0);
        *(uint4*)(&Bl[row * BKP + c * 8]) = v;
      }
    }
    __syncthreads();
    f32x4 acc0 = {0,0,0,0}, acc1 = {0,0,0,0}, acc2 = {0,0,0,0}, acc3 = {0,0,0,0};
    #pragma unroll
    for (int ks = 0; ks < 7; ++ks) {
      int k0 = ks * 32 + lq * 8;
      f16x8 a  = *(const f16x8*)(&Al[(wv * 16 + lr) * BKP + k0]);
      f16x8 b0 = *(const f16x8*)(&Bl[( 0 + lr) * BKP + k0]);
      f16x8 b1 = *(const f16x8*)(&Bl[(16 + lr) * BKP + k0]);
      f16x8 b2 = *(const f16x8*)(&Bl[(32 + lr) * BKP + k0]);
      f16x8 b3 = *(const f16x8*)(&Bl[(48 + lr) * BKP + k0]);
      acc0 = __builtin_amdgcn_mfma_f32_16x16x32_f16(a, b0, acc0, 0, 0, 0);
      acc1 = __builtin_amdgcn_mfma_f32_16x16x32_f16(a, b1, acc1, 0, 0, 0);
      acc2 = __builtin_amdgcn_mfma_f32_16x16x32_f16(a, b2, acc2, 0, 0, 0);
      acc3 = __builtin_amdgcn_mfma_f32_16x16x32_f16(a, b3, acc3, 0, 0, 0);
    }
    auto epi = [&](f32x4 acc, int nn) {
      int col = n0 + nn * 16 + lr;
      if (col < kG) {
        float bv = bias[col];
        #pragma unroll
        for (int rr = 0; rr < 4; ++rr) {
          int m = m0 + wv * 16 + lq * 4 + rr;
          X[(size_t)m * kG + col] = (f16)(acc[rr] + bv);
        }
      }
    };
    epi(acc0, 0); epi(acc1, 1); epi(acc2, 2); epi(acc3, 3);
  }
}

// ---------------- M=4 MFMA sequential LSTM core (one block = up to 4 sequences) ----------------
// 8 waves x 7 fixed tiles (N padded to 896), K=224 (7 x 16x16x32 f16 MFMA).
// Weights in rows n' = 4u+g (unit-interleaved): cell reads gates as float4/uint2.
static __device__ void lstm_core4(const f16* x0, const f16* x1, const f16* x2, const f16* x3,
                                  const f16* __restrict__ Whh,
                                  const float* h00, const float* h01,
                                  const float* h02, const float* h03,
                                  float* o0, float* o1, float* o2, float* o3,
                                  int nsteps)
{
  __shared__ __align__(16) f16 h_lds[4 * 232];   // [seq][232], k-pad [200,232) = 0
  __shared__ __align__(16) float gsh[4 * kG];    // [seq][n'=4u+g]
  int tid = threadIdx.x;
  int lane = tid & 63, wv = tid >> 6;
  int lr = lane & 15, lq = lane >> 4;

  // ---- persistent B-fragments: wave wv owns tiles 7wv..7wv+6 (tile<50 real) ----
  f16x8 bf[7][7];
  #pragma unroll
  for (int i = 0; i < 7; ++i) {
    int tile = wv * 7 + i;
    int n = tile * 16 + lr;
    const f16* wrow = Whh + (size_t)n * kH;
    bool real = (tile < 50);
    #pragma unroll
    for (int kt = 0; kt < 6; ++kt)
      bf[i][kt] = real ? *(const f16x8*)(wrow + kt * 32 + lq * 8)
                       : (f16x8){0,0,0,0,0,0,0,0};
    bf[i][6] = (real && lq == 0) ? *(const f16x8*)(wrow + 192)
                                 : (f16x8){0,0,0,0,0,0,0,0};
  }

  // ---- cell-thread pair mapping: pair0 = tid, pair1 = tid+512 (valid < 800) ----
  int q0 = tid, sp0 = q0 / kH, up0 = q0 - sp0 * kH;
  bool v1 = (tid < 288);
  int q1 = tid + 512; int sp1t = q1 / kH; int sp1 = sp1t > 3 ? 3 : sp1t;
  int up1 = q1 - sp1t * kH; if (up1 < 0 || up1 >= kH) up1 = 0;
  const f16* px0 = sel4h(sp0, x0, x1, x2, x3) + 4 * up0;
  const f16* px1 = sel4h(sp1, x0, x1, x2, x3) + 4 * up1;
  float* ow0 = sel4o(sp0, o0, o1, o2, o3);
  float* ow1 = sel4o(sp1, o0, o1, o2, o3);
  const float* ph0 = sel4f(sp0, h00, h01, h02, h03);
  const float* ph1 = sel4f(sp1, h00, h01, h02, h03);

  // ---- init h_lds: zero pads then fill h0 ----
  if (tid < 464) ((uint32_t*)h_lds)[tid] = 0u;
  __syncthreads();
  h_lds[sp0 * 232 + up0] = (f16)ph0[up0];
  if (v1) h_lds[sp1 * 232 + up1] = (f16)ph1[up1];

  float cA = 0.f, hA = 0.f, cB = 0.f, hB = 0.f;
  uint2 xcA = *(const uint2*)px0;
  uint2 xcB = v1 ? *(const uint2*)(px1) : make_uint2(0, 0);
  __syncthreads();

  for (int t = 0; t < nsteps; ++t) {
    // prefetch next step's X (hidden under MFMA phase)
    uint2 xnA = make_uint2(0, 0), xnB = make_uint2(0, 0);
    if (t + 1 < nsteps) {
      xnA = *(const uint2*)(px0 + (size_t)(t + 1) * kG);
      if (v1) xnB = *(const uint2*)(px1 + (size_t)(t + 1) * kG);
    }
    // A-fragments: rows 0-3 = sequences (lanes lr<4)
    f16x8 af[7];
    #pragma unroll
    for (int kt = 0; kt < 7; ++kt)
      af[kt] = (lr < 4) ? *(const f16x8*)(h_lds + lr * 232 + kt * 32 + lq * 8)
                        : (f16x8){0,0,0,0,0,0,0,0};
    // 7 independent acc chains, kt-outer for ILP
    f32x4 acc[7];
    #pragma unroll
    for (int i = 0; i < 7; ++i) acc[i] = (f32x4){0.f, 0.f, 0.f, 0.f};
    #pragma unroll
    for (int kt = 0; kt < 7; ++kt) {
      #pragma unroll
      for (int i = 0; i < 7; ++i)
        acc[i] = __builtin_amdgcn_mfma_f32_16x16x32_f16(af[kt], bf[i][kt], acc[i], 0, 0, 0);
    }
    // D: col n' = tile*16+lr, row(seq) = rr (lq==0)
    if (lq == 0) {
      #pragma unroll
      for (int i = 0; i < 7; ++i) {
        int tile = wv * 7 + i;
        if (tile < 50) {
          int n = tile * 16 + lr;
          gsh[0 * kG + n] = acc[i][0];
          gsh[1 * kG + n] = acc[i][1];
          gsh[2 * kG + n] = acc[i][2];
          gsh[3 * kG + n] = acc[i][3];
        }
      }
    }
    __syncthreads();
    // cell: pair0 + pair1
    {
      float4 gv = *(const float4*)(gsh + sp0 * kG + 4 * up0);
      f16x4 xv = __builtin_bit_cast(f16x4, xcA);
      float gi = gv.x + (float)xv[0];
      float gf = gv.y + (float)xv[1];
      float gg = gv.z + (float)xv[2];
      float go = gv.w + (float)xv[3];
      cA = sigf(gf) * cA + sigf(gi) * tanhf_(gg);
      hA = sigf(go) * tanhf_(cA);
      h_lds[sp0 * 232 + up0] = (f16)hA;
    }
    if (v1) {
      float4 gv = *(const float4*)(gsh + sp1 * kG + 4 * up1);
      f16x4 xv = __builtin_bit_cast(f16x4, xcB);
      float gi = gv.x + (float)xv[0];
      float gf = gv.y + (float)xv[1];
      float gg = gv.z + (float)xv[2];
      float go = gv.w + (float)xv[3];
      cB = sigf(gf) * cB + sigf(gi) * tanhf_(gg);
      hB = sigf(go) * tanhf_(cB);
      h_lds[sp1 * 232 + up1] = (f16)hB;
    }
    xcA = xnA; xcB = xnB;
    __syncthreads();
  }
  if (ow0 != nullptr) ow0[up0] = hA;
  if (v1 && ow1 != nullptr) ow1[up1] = hB;
}

// ---------------- wrappers ----------------
__global__ __launch_bounds__(512, 2) void ABHUE_lstm_batch(
    const f16* __restrict__ Xall, const f16* __restrict__ Wctx, const f16* __restrict__ Wmain,
    const float* __restrict__ h0s, float* __restrict__ sent)
{
  int b = blockIdx.x;
  if (b < 64) {
    int s0 = 4 * b, s1 = s0 + 1, s2 = s0 + 2;
    int s3 = (s0 + 3 > 254) ? 254 : s0 + 3;
    const f16* x0 = Xall + (size_t)s0 * kW * kG;
    const f16* x1 = Xall + (size_t)s1 * kW * kG;
    const f16* x2 = Xall + (size_t)s2 * kW * kG;
    const f16* x3 = Xall + (size_t)s3 * kW * kG;
    float* o0 = (s0 == kMid) ? nullptr : sent + (size_t)s0 * kH;
    float* o1 = (s1 == kMid) ? nullptr : sent + (size_t)s1 * kH;
    float* o2 = (s2 == kMid) ? nullptr : sent + (size_t)s2 * kH;
    float* o3 = (s3 == kMid || s0 + 3 > 254) ? nullptr : sent + (size_t)s3 * kH;
    lstm_core4(x0, x1, x2, x3, Wctx,
               h0s + (size_t)s0 * kH, h0s + (size_t)s1 * kH,
               h0s + (size_t)s2 * kH, h0s + (size_t)s3 * kH,
               o0, o1, o2, o3, kW);
  } else {
    // main sentence: slot 255 preactivations, Wmain, h0 = h0_sent[mid], out -> sent[mid]
    const f16* xm = Xall + (size_t)255 * kW * kG;
    const float* hm = h0s + (size_t)kMid * kH;
    lstm_core4(xm, xm, xm, xm, Wmain, hm, hm, hm, hm,
               sent + (size_t)kMid * kH, nullptr, nullptr, nullptr, kW);
  }
}

__global__ __launch_bounds__(512, 2) void ABHUE_lstm_pp(
    const f16* __restrict__ Xpp, const f16* __restrict__ Wprev, const f16* __restrict__ Wpost,
    const float* __restrict__ h0prev, const float* __restrict__ h0post, float* __restrict__ outs)
{
  int s = blockIdx.x;   // 0 = prev, 1 = post
  const f16* x = Xpp + (size_t)s * 128 * kG;
  const float* h0 = s ? h0post : h0prev;
  lstm_core4(x, x, x, x, s ? Wpost : Wprev, h0, h0, h0, h0,
             outs + (size_t)s * kH, nullptr, nullptr, nullptr, 128);
}

__global__ __launch_bounds__(256) void ABHUE_fc(
    const float* __restrict__ feat, const float* __restrict__ fcW,
    const float* __restrict__ fcb, float* __restrict__ outp)
{
  __shared__ float fs[2 * kH];
  int tid = threadIdx.x;
  for (int i = tid; i < 2 * kH; i += 256) fs[i] = feat[i];
  __syncthreads();
  if (tid < kH) {
    float acc = fcb[tid];
    #pragma unroll 4
    for (int j = 0; j < 2 * kH; ++j) acc = fmaf(fcW[tid * 2 * kH + j], fs[j], acc);
    outp[tid] = acc;
  }
}

extern "C" void kernel_launch(void* const* d_in, const int* in_sizes, int n_in,
                              void* d_out, int out_size, void* d_ws, size_t ws_size,
                              hipStream_t stream) {
  const float* utt    = (const float*)d_in[0];
  const float* h0s    = (const float*)d_in[1];
  const float* h0prev = (const float*)d_in[2];
  const float* h0post = (const float*)d_in[3];
  const float* wih[4] = {(const float*)d_in[4],  (const float*)d_in[8],
                         (const float*)d_in[12], (const float*)d_in[16]};
  const float* whh[4] = {(const float*)d_in[5],  (const float*)d_in[9],
                         (const float*)d_in[13], (const float*)d_in[17]};
  const float* bih[4] = {(const float*)d_in[6],  (const float*)d_in[10],
                         (const float*)d_in[14], (const float*)d_in[18]};
  const float* bhh[4] = {(const float*)d_in[7],  (const float*)d_in[11],
                         (const float*)d_in[15], (const float*)d_in[19]};
  const float* fcW = (const float*)d_in[20];
  const float* fcb = (const float*)d_in[21];

  char* base  = (char*)d_ws;
  f16*   Xall = (f16*)base;                   // [256 slots x 512 x 800] f16
  f16*   Wf   = (f16*)(base + OFF_WF);        // 0 ctxWih 1 ctxWhh 2 mainWih 3 mainWhh 4 prevWih 5 prevWhh 6 postWih 7 postWhh
  float* bsum = (float*)(base + OFF_BS);
  float* sent = (float*)(base + OFF_SENT);
  f16*   Xpp  = (f16*)(base + OFF_XPP);
  float* outs = (float*)(base + OFF_OUTS);

  const int WN = kG * kH;
  ABHUE_prep<<<(8 * WN + 4 * kG + 255) / 256, 256, 0, stream>>>(
      wih[0], whh[0], wih[1], whh[1], wih[2], whh[2], wih[3], whh[3],
      bih[0], bhh[0], bih[1], bhh[1], bih[2], bhh[2], bih[3], bhh[3],
      Wf, bsum);

  ABHUE_gemm_x<<<2040, 256, 0, stream>>>(utt, Wf + 0 * WN, bsum + 0, Xall, -1);
  ABHUE_gemm_x<<<8, 256, 0, stream>>>(utt + (size_t)kMid * kW * kH, Wf + 2 * WN,
                                      bsum + 800, Xall + (size_t)255 * kW * kG, -1);
  ABHUE_lstm_batch<<<65, 512, 0, stream>>>(Xall, Wf + 1 * WN, Wf + 3 * WN, h0s, sent);
  ABHUE_gemm_x<<<2, 256, 0, stream>>>(sent, Wf + 4 * WN, bsum + 1600, Xpp, -1);
  ABHUE_gemm_x<<<2, 256, 0, stream>>>(sent, Wf + 6 * WN, bsum + 2400, Xpp + (size_t)128 * kG, 254);
  ABHUE_lstm_pp<<<2, 512, 0, stream>>>(Xpp, Wf + 5 * WN, Wf + 7 * WN, h0prev, h0post, outs);
  ABHUE_fc<<<1, 256, 0, stream>>>(outs, fcW, fcb, (float*)d_out);
}

// Round 7
// 1308.987 us; speedup vs baseline: 1.9489x; 1.9489x over previous
//
#include <hip/hip_runtime.h>
#include <hip/hip_fp16.h>
#include <cstdint>

typedef _Float16 f16;
typedef _Float16 f16x2 __attribute__((ext_vector_type(2)));
typedef _Float16 f16x4 __attribute__((ext_vector_type(4)));
typedef _Float16 f16x8 __attribute__((ext_vector_type(8)));
typedef float f32x4 __attribute__((ext_vector_type(4)));

#define kH 200
#define kG 800
#define kS 255
#define kW 512
#define kMid 127

// ---- ws layout (byte offsets), total ~213 MB ----
#define OFF_WF   209715200ULL   // 8 x [800x200] f16 weight matrices (rows permuted n'=4u+g)
#define OFF_BS   212275200ULL   // 4 x [800] f32 combined biases (permuted)
#define OFF_SENT 212288000ULL   // [255x200] f32 sentence embeddings
#define OFF_XPP  212492032ULL   // 2 x [128x800] f16 prev/post preactivations
#define OFF_OUTS 212901632ULL   // [400] f32 prev_out|post_out

__device__ __forceinline__ float sigf(float x) { return 1.0f / (1.0f + __expf(-x)); }
__device__ __forceinline__ float tanhf_(float x) { return 1.0f - 2.0f / (__expf(2.0f * x) + 1.0f); }

// ---------------- prep: f32->f16 weights (gate-unit interleaved rows), biases ----------------
// dst row n' = 4u+g  <->  src row n = g*200+u  (applied to all Wih/Whh and biases).
__global__ __launch_bounds__(256) void ABHUE_prep(
    const float* W0, const float* W1, const float* W2, const float* W3,
    const float* W4, const float* W5, const float* W6, const float* W7,
    const float* B0i, const float* B0h, const float* B1i, const float* B1h,
    const float* B2i, const float* B2h, const float* B3i, const float* B3h,
    f16* wdst, float* bdst)
{
  int idx = blockIdx.x * 256 + threadIdx.x;
  const int WN = kG * kH;  // 160000
  if (idx < 8 * WN) {
    int m = idx / WN, off = idx % WN;
    const float* src = m == 0 ? W0 : m == 1 ? W1 : m == 2 ? W2 : m == 3 ? W3
                     : m == 4 ? W4 : m == 5 ? W5 : m == 6 ? W6 : W7;
    int np = off / kH, k = off - np * kH;
    int u = np >> 2, g = np & 3;
    wdst[idx] = (f16)src[(size_t)(g * kH + u) * kH + k];
  } else {
    int j = idx - 8 * WN;
    if (j < 4 * kG) {
      int st = j / kG, np = j - st * kG;
      int u = np >> 2, g = np & 3;
      int n = g * kH + u;
      const float* bi = st == 0 ? B0i : st == 1 ? B1i : st == 2 ? B2i : B3i;
      const float* bh = st == 0 ? B0h : st == 1 ? B1h : st == 2 ? B2h : B3h;
      bdst[j] = bi[n] + bh[n];
    }
  }
}

// ---------------- GEMM: X[m, 0..799] = A[m,:200] @ W[800,200]^T + bias ----------------
#define BM 64
#define BKP 232
__global__ __launch_bounds__(256) void ABHUE_gemm_x(
    const float* __restrict__ A, const f16* __restrict__ Wf,
    const float* __restrict__ bias, f16* __restrict__ X, int rev)
{
  __shared__ __align__(16) f16 Al[BM * BKP];
  __shared__ __align__(16) f16 Bl[BM * BKP];
  int tid = threadIdx.x;
  int m0 = blockIdx.x * BM;

  #pragma unroll
  for (int it = 0; it < 4; ++it) {
    int idx = tid + 256 * it;
    int row = idx >> 4, dw = idx & 15;
    *(uint32_t*)(&Al[row * BKP + 200 + dw * 2]) = 0u;
    *(uint32_t*)(&Bl[row * BKP + 200 + dw * 2]) = 0u;
  }
  for (int it = 0; it < 13; ++it) {
    int q = tid + 256 * it;
    if (q < 3200) {
      int row = q / 50, c = q % 50;
      int rg = m0 + row; if (rev >= 0) rg = rev - rg;
      const float4 v = *(const float4*)(A + (size_t)rg * kH + c * 4);
      f16x2 p0; p0[0] = (f16)v.x; p0[1] = (f16)v.y;
      f16x2 p1; p1[0] = (f16)v.z; p1[1] = (f16)v.w;
      uint2 pk; pk.x = __builtin_bit_cast(uint32_t, p0); pk.y = __builtin_bit_cast(uint32_t, p1);
      *(uint2*)(&Al[row * BKP + c * 4]) = pk;
    }
  }
  int wv = tid >> 6, lane = tid & 63;
  int lr = lane & 15, lq = lane >> 4;

  for (int nt = 0; nt < 13; ++nt) {
    int n0 = nt * 64;
    __syncthreads();
    for (int it = 0; it < 7; ++it) {
      int q = tid + 256 * it;
      if (q < 1600) {
        int row = q / 25, c = q % 25;
        int ng = n0 + row;
        uint4 v = (ng < kG) ? *(const uint4*)(Wf + (size_t)ng * kH + c * 8)
                            : make_uint4(0, 0, 0, 0);
        *(uint4*)(&Bl[row * BKP + c * 8]) = v;
      }
    }
    __syncthreads();
    f32x4 acc0 = {0,0,0,0}, acc1 = {0,0,0,0}, acc2 = {0,0,0,0}, acc3 = {0,0,0,0};
    #pragma unroll
    for (int ks = 0; ks < 7; ++ks) {
      int k0 = ks * 32 + lq * 8;
      f16x8 a  = *(const f16x8*)(&Al[(wv * 16 + lr) * BKP + k0]);
      f16x8 b0 = *(const f16x8*)(&Bl[( 0 + lr) * BKP + k0]);
      f16x8 b1 = *(const f16x8*)(&Bl[(16 + lr) * BKP + k0]);
      f16x8 b2 = *(const f16x8*)(&Bl[(32 + lr) * BKP + k0]);
      f16x8 b3 = *(const f16x8*)(&Bl[(48 + lr) * BKP + k0]);
      acc0 = __builtin_amdgcn_mfma_f32_16x16x32_f16(a, b0, acc0, 0, 0, 0);
      acc1 = __builtin_amdgcn_mfma_f32_16x16x32_f16(a, b1, acc1, 0, 0, 0);
      acc2 = __builtin_amdgcn_mfma_f32_16x16x32_f16(a, b2, acc2, 0, 0, 0);
      acc3 = __builtin_amdgcn_mfma_f32_16x16x32_f16(a, b3, acc3, 0, 0, 0);
    }
    auto epi = [&](f32x4 acc, int nn) {
      int col = n0 + nn * 16 + lr;
      if (col < kG) {
        float bv = bias[col];
        #pragma unroll
        for (int rr = 0; rr < 4; ++rr) {
          int m = m0 + wv * 16 + lq * 4 + rr;
          X[(size_t)m * kG + col] = (f16)(acc[rr] + bv);
        }
      }
    };
    epi(acc0, 0); epi(acc1, 1); epi(acc2, 2); epi(acc3, 3);
  }
}

// ---------------- M=1 MFMA sequential LSTM (one block = one sequence) ----------------
// R3-proven register budget (bf[7][7] guarded + <=2 live acc). New vs R3:
//  - weights/bias/X in gate-unit permuted order n'=4u+g -> cell is wave-local
//  - ONE barrier/step: h double-buffer (read hbuf[t&1], write hbuf[(t&1)^1])
//  - A-frag read as same-address broadcast (rows 1-15 of A are don't-care at M=1)
//  - MFMA in 2-chain interleaved pairs for latency cover without reg blowup
static __device__ void lstm_m1(const f16* __restrict__ X, const f16* __restrict__ Whh,
                               const float* __restrict__ h0, int nsteps,
                               float* __restrict__ out)
{
  __shared__ __align__(16) f16 hbuf[2][224];   // [buf][k], pads [200,224) = 0
  __shared__ __align__(16) float gsh[kG];      // per-wave slices, n' = 4u+g
  int tid = threadIdx.x;
  int lane = tid & 63, wv = tid >> 6;
  int lr = lane & 15, lq = lane >> 4;
  int t0 = (50 * wv) >> 3;                     // wave tile range [t0, t0+cnt)
  int cnt = ((50 * (wv + 1)) >> 3) - t0;       // 6 or 7

  // ---- persistent B-fragments (VGPR/AGPR resident) ----
  f16x8 bf[7][7];
  #pragma unroll
  for (int i = 0; i < 7; ++i) {
    if (i < cnt) {
      int n = (t0 + i) * 16 + lr;
      const f16* wrow = Whh + (size_t)n * kH;
      #pragma unroll
      for (int kt = 0; kt < 6; ++kt)
        bf[i][kt] = *(const f16x8*)(wrow + kt * 32 + lq * 8);
      bf[i][6] = (lq == 0) ? *(const f16x8*)(wrow + 192)
                           : (f16x8){0,0,0,0,0,0,0,0};   // zero: avoid NaN*0 in k-pad
    }
  }

  // ---- cell lane mapping: lane l < 4*cnt owns unit ul ----
  int ul = 4 * t0 + lane;
  bool cellp = (lane < 4 * cnt);

  if (tid < 24) { hbuf[0][200 + tid] = (f16)0; hbuf[1][200 + tid] = (f16)0; }
  if (cellp) hbuf[0][ul] = (f16)h0[ul];
  float cst = 0.f, hout = 0.f;
  uint2 xc = make_uint2(0, 0);
  if (cellp) xc = *(const uint2*)(X + 4 * ul);
  __syncthreads();

  for (int t = 0; t < nsteps; ++t) {
    const f16* hb = hbuf[t & 1];
    // prefetch next step's X (VMEM latency hidden under MFMA phase)
    uint2 xn = make_uint2(0, 0);
    if (cellp && t + 1 < nsteps)
      xn = *(const uint2*)(X + (size_t)(t + 1) * kG + 4 * ul);

    // A-fragments: every lane reads the same per-lq address (LDS broadcast, free)
    f16x8 af[7];
    #pragma unroll
    for (int kt = 0; kt < 7; ++kt)
      af[kt] = *(const f16x8*)(hb + kt * 32 + lq * 8);

    // MFMA: pairs of tiles -> 2 interleaved acc chains (only 8 acc regs live)
    #pragma unroll
    for (int ip = 0; ip < 3; ++ip) {
      f32x4 a0 = {0.f,0.f,0.f,0.f}, a1 = {0.f,0.f,0.f,0.f};
      #pragma unroll
      for (int kt = 0; kt < 7; ++kt) {
        a0 = __builtin_amdgcn_mfma_f32_16x16x32_f16(af[kt], bf[2*ip][kt], a0, 0, 0, 0);
        a1 = __builtin_amdgcn_mfma_f32_16x16x32_f16(af[kt], bf[2*ip+1][kt], a1, 0, 0, 0);
      }
      if (lq == 0) {          // D row 0 lives in lanes 0-15, acc[0]
        gsh[(t0 + 2*ip) * 16 + lr]     = a0[0];
        gsh[(t0 + 2*ip + 1) * 16 + lr] = a1[0];
      }
    }
    if (cnt == 7) {
      f32x4 a0 = {0.f,0.f,0.f,0.f};
      #pragma unroll
      for (int kt = 0; kt < 7; ++kt)
        a0 = __builtin_amdgcn_mfma_f32_16x16x32_f16(af[kt], bf[6][kt], a0, 0, 0, 0);
      if (lq == 0) gsh[(t0 + 6) * 16 + lr] = a0[0];
    }

    // same-wave cross-lane gsh handoff: force LDS writes complete, block reordering
    asm volatile("s_waitcnt lgkmcnt(0)" ::: "memory");

    if (cellp) {
      float4 gv = *(const float4*)(gsh + 4 * ul);   // own-wave slice
      f16x4 xv = __builtin_bit_cast(f16x4, xc);
      float gi = gv.x + (float)xv[0];
      float gf = gv.y + (float)xv[1];
      float gg = gv.z + (float)xv[2];
      float go = gv.w + (float)xv[3];
      cst  = sigf(gf) * cst + sigf(gi) * tanhf_(gg);
      hout = sigf(go) * tanhf_(cst);
      hbuf[(t & 1) ^ 1][ul] = (f16)hout;            // write OTHER buffer
    }
    xc = xn;
    __syncthreads();                                 // single barrier per step
  }
  if (out != nullptr && cellp) out[ul] = hout;
}

// ---------------- wrappers ----------------
__global__ __launch_bounds__(512, 2) void ABHUE_lstm_batch(
    const f16* __restrict__ Xall, const f16* __restrict__ Wctx, const f16* __restrict__ Wmain,
    const float* __restrict__ h0s, float* __restrict__ sent)
{
  int s = blockIdx.x;                       // 0..254 ctx, 255 = main(mid)
  const f16* X = Xall + (size_t)s * kW * kG;
  const f16* Wh = (s == 255) ? Wmain : Wctx;
  int hrow = (s == 255) ? kMid : s;
  const float* h0 = h0s + (size_t)hrow * kH;
  float* out = (s == kMid) ? nullptr : sent + (size_t)hrow * kH;  // ctx[mid] discarded
  lstm_m1(X, Wh, h0, kW, out);
}

__global__ __launch_bounds__(512, 2) void ABHUE_lstm_pp(
    const f16* __restrict__ Xpp, const f16* __restrict__ Wprev, const f16* __restrict__ Wpost,
    const float* __restrict__ h0prev, const float* __restrict__ h0post, float* __restrict__ outs)
{
  int s = blockIdx.x;   // 0 = prev, 1 = post
  lstm_m1(Xpp + (size_t)s * 128 * kG, s ? Wpost : Wprev, s ? h0post : h0prev, 128,
          outs + (size_t)s * kH);
}

__global__ __launch_bounds__(256) void ABHUE_fc(
    const float* __restrict__ feat, const float* __restrict__ fcW,
    const float* __restrict__ fcb, float* __restrict__ outp)
{
  __shared__ float fs[2 * kH];
  int tid = threadIdx.x;
  for (int i = tid; i < 2 * kH; i += 256) fs[i] = feat[i];
  __syncthreads();
  if (tid < kH) {
    float acc = fcb[tid];
    #pragma unroll 4
    for (int j = 0; j < 2 * kH; ++j) acc = fmaf(fcW[tid * 2 * kH + j], fs[j], acc);
    outp[tid] = acc;
  }
}

extern "C" void kernel_launch(void* const* d_in, const int* in_sizes, int n_in,
                              void* d_out, int out_size, void* d_ws, size_t ws_size,
                              hipStream_t stream) {
  const float* utt    = (const float*)d_in[0];
  const float* h0s    = (const float*)d_in[1];
  const float* h0prev = (const float*)d_in[2];
  const float* h0post = (const float*)d_in[3];
  const float* wih[4] = {(const float*)d_in[4],  (const float*)d_in[8],
                         (const float*)d_in[12], (const float*)d_in[16]};
  const float* whh[4] = {(const float*)d_in[5],  (const float*)d_in[9],
                         (const float*)d_in[13], (const float*)d_in[17]};
  const float* bih[4] = {(const float*)d_in[6],  (const float*)d_in[10],
                         (const float*)d_in[14], (const float*)d_in[18]};
  const float* bhh[4] = {(const float*)d_in[7],  (const float*)d_in[11],
                         (const float*)d_in[15], (const float*)d_in[19]};
  const float* fcW = (const float*)d_in[20];
  const float* fcb = (const float*)d_in[21];

  char* base  = (char*)d_ws;
  f16*   Xall = (f16*)base;                   // [256 slots x 512 x 800] f16
  f16*   Wf   = (f16*)(base + OFF_WF);        // 0 ctxWih 1 ctxWhh 2 mainWih 3 mainWhh 4 prevWih 5 prevWhh 6 postWih 7 postWhh
  float* bsum = (float*)(base + OFF_BS);
  float* sent = (float*)(base + OFF_SENT);
  f16*   Xpp  = (f16*)(base + OFF_XPP);
  float* outs = (float*)(base + OFF_OUTS);

  const int WN = kG * kH;
  ABHUE_prep<<<(8 * WN + 4 * kG + 255) / 256, 256, 0, stream>>>(
      wih[0], whh[0], wih[1], whh[1], wih[2], whh[2], wih[3], whh[3],
      bih[0], bhh[0], bih[1], bhh[1], bih[2], bhh[2], bih[3], bhh[3],
      Wf, bsum);

  ABHUE_gemm_x<<<2040, 256, 0, stream>>>(utt, Wf + 0 * WN, bsum + 0, Xall, -1);
  ABHUE_gemm_x<<<8, 256, 0, stream>>>(utt + (size_t)kMid * kW * kH, Wf + 2 * WN,
                                      bsum + 800, Xall + (size_t)255 * kW * kG, -1);
  ABHUE_lstm_batch<<<256, 512, 0, stream>>>(Xall, Wf + 1 * WN, Wf + 3 * WN, h0s, sent);
  ABHUE_gemm_x<<<2, 256, 0, stream>>>(sent, Wf + 4 * WN, bsum + 1600, Xpp, -1);
  ABHUE_gemm_x<<<2, 256, 0, stream>>>(sent, Wf + 6 * WN, bsum + 2400, Xpp + (size_t)128 * kG, 254);
  ABHUE_lstm_pp<<<2, 512, 0, stream>>>(Xpp, Wf + 5 * WN, Wf + 7 * WN, h0prev, h0post, outs);
  ABHUE_fc<<<1, 256, 0, stream>>>(outs, fcW, fcb, (float*)d_out);
}